// Round 11
// baseline (138.663 us; speedup 1.0000x reference)
//
#include <hip/hip_runtime.h>

typedef __attribute__((ext_vector_type(8))) short short8;
typedef __attribute__((ext_vector_type(4))) float f32x4;
typedef __attribute__((ext_vector_type(4))) unsigned int u32x4;

// Measurement round: loop kscore's body REPS times (idempotent) so the kscore
// dispatch rises above the ~40us harness poison-fills and becomes visible in
// the rocprof top-5 with full counters.  dur_us ~= base + (REPS-1)*K.
#define KSCORE_REPS 8

static __device__ inline unsigned short f2bf(float x) {
    unsigned int u = __float_as_uint(x);
    u = (u + 0x7FFFu + ((u >> 16) & 1u)) >> 16;
    return (unsigned short)u;
}

// ---------------- Kernel 1: L2-normalize rows, cast to bf16 ----------------
__global__ __launch_bounds__(256) void knorm(const float* __restrict__ feats,
                                             const float* __restrict__ nfeats,
                                             unsigned short* __restrict__ fb,
                                             unsigned short* __restrict__ gb) {
    int row = blockIdx.x * 4 + (threadIdx.x >> 6);
    int lane = threadIdx.x & 63;
    const float* src;
    unsigned short* dst;
    if (row < 4096) { src = feats + row * 128;           dst = fb + row * 128; }
    else            { src = nfeats + (row - 4096) * 128; dst = gb + (row - 4096) * 128; }
    float2 v = ((const float2*)src)[lane];
    float ss = v.x * v.x + v.y * v.y;
    #pragma unroll
    for (int d = 32; d; d >>= 1) ss += __shfl_xor(ss, d);
    float inv = 1.0f / sqrtf(ss);
    ushort2 o;
    o.x = f2bf(v.x * inv);
    o.y = f2bf(v.y * inv);
    ((ushort2*)dst)[lane] = o;
}

// ---------------- Kernel 2: partial max_q dot(f[p], g[q]) via MFMA ----------
// R9 structure exactly; phase-2 body looped KSCORE_REPS times for measurement.
__global__ __launch_bounds__(256, 2) void kscore(const unsigned short* __restrict__ fb,
                                                 const unsigned short* __restrict__ gb,
                                                 float* __restrict__ sp_part) {
    __shared__ char gtile[2][8192];          // 2 x 8KB, XOR-swizzled image
    const int tid = threadIdx.x;
    const int lane = tid & 63;
    const int wave = tid >> 6;               // 0..3 = p-subtile
    const int l15 = lane & 15, lhi = lane >> 4;
    const int m = blockIdx.x;
    const int ptile = blockIdx.y >> 2, qq = blockIdx.y & 3;
    const int rowbase = ptile * 256 + wave * 64;   // global f row in [0,4096)

    const unsigned short* gBase = gb + ((size_t)m * 1024 + qq * 256) * 128;

    const int r0 = tid >> 4, s0 = tid & 15;
    const int r1 = r0 + 16;
    const unsigned short* gsrc0 = gBase + (size_t)r0 * 128 + s0 * 8;
    const unsigned short* gsrc1 = gBase + (size_t)r1 * 128 + s0 * 8;
    const int wofs0 = (r0 * 256 + s0 * 16) ^ ((r0 & 7) << 4);
    const int wofs1 = (r1 * 256 + s0 * 16) ^ ((r1 & 7) << 4);

    // A fragments: 4 p-groups x 4 k-groups (64 VGPR), persistent
    short8 a[4][4];
    #pragma unroll
    for (int pg = 0; pg < 4; pg++) {
        const unsigned short* arow = fb + (size_t)(rowbase + pg * 16 + l15) * 128;
        #pragma unroll
        for (int kk = 0; kk < 4; kk++)
            a[pg][kk] = *(const short8*)(arow + kk * 32 + lhi * 8);
    }

    f32x4 mx[4];

    #pragma unroll 1
    for (int rep = 0; rep < KSCORE_REPS; ++rep) {
        #pragma unroll
        for (int pg = 0; pg < 4; pg++)
            #pragma unroll
            for (int i = 0; i < 4; i++) mx[pg][i] = -1e30f;

        // prologue: tile0 -> L0; tile1 loads left in flight
        u32x4 t0a = *(const u32x4*)(gsrc0);
        u32x4 t0b = *(const u32x4*)(gsrc1);
        *(u32x4*)(gtile[0] + wofs0) = t0a;
        *(u32x4*)(gtile[0] + wofs1) = t0b;
        u32x4 stna = *(const u32x4*)(gsrc0 + 32 * 128);
        u32x4 stnb = *(const u32x4*)(gsrc1 + 32 * 128);
        asm volatile("s_waitcnt lgkmcnt(0)" ::: "memory");
        __builtin_amdgcn_s_barrier();

        #pragma unroll
        for (int t = 0; t < 8; t++) {
            __builtin_amdgcn_sched_barrier(0);
            u32x4 s2a, s2b;
            if (t < 6) {
                s2a = *(const u32x4*)(gsrc0 + (size_t)(t + 2) * 32 * 128);
                s2b = *(const u32x4*)(gsrc1 + (size_t)(t + 2) * 32 * 128);
            }
            if (t < 7) {
                *(u32x4*)(gtile[(t + 1) & 1] + wofs0) = stna;
                *(u32x4*)(gtile[(t + 1) & 1] + wofs1) = stnb;
            }
            const char* tp = gtile[t & 1];
            #pragma unroll
            for (int qt = 0; qt < 2; qt++) {
                const int r = qt * 16 + l15;
                const int rowoff = r * 256;
                const int swz = (r & 7) << 4;
                f32x4 acc[4];
                #pragma unroll
                for (int pg = 0; pg < 4; pg++)
                    #pragma unroll
                    for (int i = 0; i < 4; i++) acc[pg][i] = 0.f;
                #pragma unroll
                for (int kk = 0; kk < 4; kk++) {
                    short8 b = *(const short8*)(tp + ((rowoff + kk * 64 + lhi * 16) ^ swz));
                    #pragma unroll
                    for (int pg = 0; pg < 4; pg++)
                        acc[pg] = __builtin_amdgcn_mfma_f32_16x16x32_bf16(a[pg][kk], b, acc[pg], 0, 0, 0);
                }
                #pragma unroll
                for (int pg = 0; pg < 4; pg++)
                    #pragma unroll
                    for (int i = 0; i < 4; i++) mx[pg][i] = fmaxf(mx[pg][i], acc[pg][i]);
            }
            if (t < 6) { stna = s2a; stnb = s2b; }
            asm volatile("s_waitcnt lgkmcnt(0)" ::: "memory");
            __builtin_amdgcn_s_barrier();
        }
    }

    // reduce max over the 16 q-columns (C/D col = lane&15)
    #pragma unroll
    for (int pg = 0; pg < 4; pg++)
        #pragma unroll
        for (int i = 0; i < 4; i++) {
            float v = mx[pg][i];
            v = fmaxf(v, __shfl_xor(v, 1));
            v = fmaxf(v, __shfl_xor(v, 2));
            v = fmaxf(v, __shfl_xor(v, 4));
            v = fmaxf(v, __shfl_xor(v, 8));
            mx[pg][i] = v;
        }
    if (l15 == 0) {
        #pragma unroll
        for (int pg = 0; pg < 4; pg++)
            #pragma unroll
            for (int i = 0; i < 4; i++) {
                int row = rowbase + pg * 16 + lhi * 4 + i;   // [0,4096)
                int n = row >> 10, p = row & 1023;
                sp_part[((size_t)(n * 8 + m) * 4 + qq) * 1024 + p] = mx[pg][i];
            }
    }
}

// --------- Kernel 3: fused fold + scores + bilinear upsample ---------------
__global__ __launch_bounds__(256) void kfinal(const float* __restrict__ sp_part,
                                              const float* __restrict__ mask,
                                              float* __restrict__ out) {
    const int n = blockIdx.y;
    const int bx = blockIdx.x;
    const int t = threadIdx.x;
    float* pix = out + 4;

    if (bx == 64) {  // ---- scores[n] = mean_m max_p dist ----
        __shared__ float smax[4];
        float acc = 0.f;
        for (int m = 0; m < 8; m++) {
            const float* base = sp_part + (size_t)(n * 8 + m) * 4 * 1024;
            float lm = -1e30f;
            #pragma unroll
            for (int i = 0; i < 4; i++) {
                int p = i * 256 + t;
                float dot = fmaxf(fmaxf(base[p], base[1024 + p]),
                                  fmaxf(base[2048 + p], base[3072 + p]));
                float d = sqrtf(fmaxf(2.0f - 2.0f * dot, 0.0f)) * 0.5f * mask[n * 1024 + p];
                lm = fmaxf(lm, d);
            }
            #pragma unroll
            for (int d = 32; d; d >>= 1) lm = fmaxf(lm, __shfl_xor(lm, d));
            if ((t & 63) == 0) smax[t >> 6] = lm;
            __syncthreads();
            if (t == 0) acc += fmaxf(fmaxf(smax[0], smax[1]), fmaxf(smax[2], smax[3]));
            __syncthreads();
        }
        if (t == 0) out[n] = acc * 0.125f;
        return;
    }

    // ---- output band: rows [bx*8, bx*8+8); needs 2 consecutive patch rows ----
    __shared__ float sp_row[2][32];
    const int band = bx * 8;
    const int pr_lo = (int)floorf((band + 0.5f) * 0.0625f - 0.5f);
    const int row0 = min(max(pr_lo, 0), 31);
    const int row1 = min(max(pr_lo + 1, 0), 31);
    {
        int v = t >> 2, sub = t & 3;          // 64 values x 4 threads
        int vr = v >> 5, vc = v & 31;
        int p = (vr ? row1 : row0) * 32 + vc;
        float sum = 0.f;
        #pragma unroll
        for (int mi = 0; mi < 2; mi++) {
            int m = sub * 2 + mi;
            const float* base = sp_part + (size_t)(n * 8 + m) * 4 * 1024 + p;
            float dot = fmaxf(fmaxf(base[0], base[1024]),
                              fmaxf(base[2048], base[3072]));
            sum += sqrtf(fmaxf(2.0f - 2.0f * dot, 0.0f)) * 0.5f;
        }
        sum *= mask[n * 1024 + p];
        sum += __shfl_xor(sum, 1);
        sum += __shfl_xor(sum, 2);
        if (sub == 0) sp_row[vr][vc] = sum * 0.125f;
    }
    __syncthreads();
    #pragma unroll
    for (int i = 0; i < 16; i++) {
        int idx = i * 256 + t;
        int yl = idx >> 9, x = idx & 511;
        int y = band + yl;
        float fy = (y + 0.5f) * 0.0625f - 0.5f;
        float ty = fy - (float)pr_lo;          // rows {pr_lo, pr_lo+1}; clamped dup at edges
        float fx = (x + 0.5f) * 0.0625f - 0.5f;
        float xf = floorf(fx);
        float tx = fx - xf;
        int x0 = (int)xf;
        int x0c = min(max(x0, 0), 31), x1c = min(max(x0 + 1, 0), 31);
        float v00 = sp_row[0][x0c], v01 = sp_row[0][x1c];
        float v10 = sp_row[1][x0c], v11 = sp_row[1][x1c];
        float v0 = v00 + tx * (v01 - v00);
        float v1 = v10 + tx * (v11 - v10);
        pix[(size_t)n * 262144 + (size_t)y * 512 + x] = v0 + ty * (v1 - v0);
    }
}

extern "C" void kernel_launch(void* const* d_in, const int* in_sizes, int n_in,
                              void* d_out, int out_size, void* d_ws, size_t ws_size,
                              hipStream_t stream) {
    const float* feats = (const float*)d_in[0];           // [4,1024,128] f32
    const float* nfeats = (const float*)d_in[1];          // [8,1024,128] f32
    const float* mask = (const float*)d_in[2];            // [4,1024] f32
    float* out = (float*)d_out;                           // [4] scores + [4,512,512]

    unsigned short* fb = (unsigned short*)d_ws;                         // 1 MB
    unsigned short* gb = fb + 4096 * 128;                               // 2 MB
    float* sp_part = (float*)((char*)d_ws + 3u * 1024u * 1024u);        // 512 KB

    knorm<<<3072, 256, 0, stream>>>(feats, nfeats, fb, gb);
    kscore<<<dim3(8, 64), 256, 0, stream>>>(fb, gb, sp_part);
    kfinal<<<dim3(65, 4), 256, 0, stream>>>(sp_part, mask, out);
}

// Round 12
// 38.785 us; speedup vs baseline: 3.5752x; 3.5752x over previous
//
#include <hip/hip_runtime.h>

typedef __attribute__((ext_vector_type(8))) short short8;
typedef __attribute__((ext_vector_type(4))) float f32x4;
typedef __attribute__((ext_vector_type(4))) unsigned int u32x4;

static __device__ inline unsigned short f2bf(float x) {
    unsigned int u = __float_as_uint(x);
    u = (u + 0x7FFFu + ((u >> 16) & 1u)) >> 16;
    return (unsigned short)u;
}

// ---------------- Kernel 1: L2-normalize rows, cast to bf16 ----------------
__global__ __launch_bounds__(256) void knorm(const float* __restrict__ feats,
                                             const float* __restrict__ nfeats,
                                             unsigned short* __restrict__ fb,
                                             unsigned short* __restrict__ gb) {
    int row = blockIdx.x * 4 + (threadIdx.x >> 6);
    int lane = threadIdx.x & 63;
    const float* src;
    unsigned short* dst;
    if (row < 4096) { src = feats + row * 128;           dst = fb + row * 128; }
    else            { src = nfeats + (row - 4096) * 128; dst = gb + (row - 4096) * 128; }
    float2 v = ((const float2*)src)[lane];
    float ss = v.x * v.x + v.y * v.y;
    #pragma unroll
    for (int d = 32; d; d >>= 1) ss += __shfl_xor(ss, d);
    float inv = 1.0f / sqrtf(ss);
    ushort2 o;
    o.x = f2bf(v.x * inv);
    o.y = f2bf(v.y * inv);
    ((ushort2*)dst)[lane] = o;
}

// ---------------- Kernel 2: partial max_q dot(f[p], g[q]) via MFMA ----------
// grid (8 m, 128 = ptile*8+qq), 256 thr = 4 waves; block = 256p x 128q.
// 1024 blocks = 4 blocks/CU (launch_bounds 256,4; VGPR<=128): 4 INDEPENDENT
// barrier domains per CU so staging stalls overlap other blocks' MFMA.
// (R11 counters: 2 blocks/CU -> 21% occupancy, MfmaUtil 21%, 78% stall.)
// Reg-staged XOR-swizzled LDS double-buffer; 4 phases of 32 q-rows.
__global__ __launch_bounds__(256, 4) void kscore(const unsigned short* __restrict__ fb,
                                                 const unsigned short* __restrict__ gb,
                                                 float* __restrict__ sp_part) {
    __shared__ char gtile[2][8192];          // 2 x 8KB, XOR-swizzled image
    const int tid = threadIdx.x;
    const int lane = tid & 63;
    const int wave = tid >> 6;               // 0..3 = p-subtile
    const int l15 = lane & 15, lhi = lane >> 4;
    const int m = blockIdx.x;
    const int ptile = blockIdx.y >> 3, qq = blockIdx.y & 7;
    const int rowbase = ptile * 256 + wave * 64;   // global f row in [0,4096)

    const unsigned short* gBase = gb + ((size_t)m * 1024 + qq * 128) * 128;

    // staging: 2 granules (16B)/thread; LINEAR global read, swizzle on ds_write;
    // LDS image = (r*256+s*16)^((r&7)<<4), r=0..31, s=0..15
    const int r0 = tid >> 4, s0 = tid & 15;
    const int r1 = r0 + 16;
    const unsigned short* gsrc0 = gBase + (size_t)r0 * 128 + s0 * 8;
    const unsigned short* gsrc1 = gBase + (size_t)r1 * 128 + s0 * 8;
    const int wofs0 = (r0 * 256 + s0 * 16) ^ ((r0 & 7) << 4);
    const int wofs1 = (r1 * 256 + s0 * 16) ^ ((r1 & 7) << 4);

    // A fragments: 4 p-groups x 4 k-groups (64 VGPR), persistent
    short8 a[4][4];
    #pragma unroll
    for (int pg = 0; pg < 4; pg++) {
        const unsigned short* arow = fb + (size_t)(rowbase + pg * 16 + l15) * 128;
        #pragma unroll
        for (int kk = 0; kk < 4; kk++)
            a[pg][kk] = *(const short8*)(arow + kk * 32 + lhi * 8);
    }

    f32x4 mx[4];
    #pragma unroll
    for (int pg = 0; pg < 4; pg++)
        #pragma unroll
        for (int i = 0; i < 4; i++) mx[pg][i] = -1e30f;

    // prologue: tile0 -> L0; tile1 loads left in flight
    u32x4 t0a = *(const u32x4*)(gsrc0);
    u32x4 t0b = *(const u32x4*)(gsrc1);
    *(u32x4*)(gtile[0] + wofs0) = t0a;
    *(u32x4*)(gtile[0] + wofs1) = t0b;
    u32x4 stna = *(const u32x4*)(gsrc0 + 32 * 128);
    u32x4 stnb = *(const u32x4*)(gsrc1 + 32 * 128);
    asm volatile("s_waitcnt lgkmcnt(0)" ::: "memory");
    __builtin_amdgcn_s_barrier();

    #pragma unroll
    for (int t = 0; t < 4; t++) {
        __builtin_amdgcn_sched_barrier(0);
        // issue tile t+2 loads (stay in flight across this phase)
        u32x4 s2a, s2b;
        if (t < 2) {
            s2a = *(const u32x4*)(gsrc0 + (size_t)(t + 2) * 32 * 128);
            s2b = *(const u32x4*)(gsrc1 + (size_t)(t + 2) * 32 * 128);
        }
        // write tile t+1 into the buffer consumed last phase (safe post-barrier)
        if (t < 3) {
            *(u32x4*)(gtile[(t + 1) & 1] + wofs0) = stna;
            *(u32x4*)(gtile[(t + 1) & 1] + wofs1) = stnb;
        }
        // compute tile t: 2 q-subtiles x 4 kk x 4 pg = 32 MFMA
        const char* tp = gtile[t & 1];
        #pragma unroll
        for (int qt = 0; qt < 2; qt++) {
            const int r = qt * 16 + l15;
            const int rowoff = r * 256;
            const int swz = (r & 7) << 4;
            f32x4 acc[4];
            #pragma unroll
            for (int pg = 0; pg < 4; pg++)
                #pragma unroll
                for (int i = 0; i < 4; i++) acc[pg][i] = 0.f;
            #pragma unroll
            for (int kk = 0; kk < 4; kk++) {
                short8 b = *(const short8*)(tp + ((rowoff + kk * 64 + lhi * 16) ^ swz));
                #pragma unroll
                for (int pg = 0; pg < 4; pg++)
                    acc[pg] = __builtin_amdgcn_mfma_f32_16x16x32_bf16(a[pg][kk], b, acc[pg], 0, 0, 0);
            }
            #pragma unroll
            for (int pg = 0; pg < 4; pg++)
                #pragma unroll
                for (int i = 0; i < 4; i++) mx[pg][i] = fmaxf(mx[pg][i], acc[pg][i]);
        }
        if (t < 2) { stna = s2a; stnb = s2b; }
        asm volatile("s_waitcnt lgkmcnt(0)" ::: "memory");
        __builtin_amdgcn_s_barrier();
    }

    // reduce max over the 16 q-columns (C/D col = lane&15)
    #pragma unroll
    for (int pg = 0; pg < 4; pg++)
        #pragma unroll
        for (int i = 0; i < 4; i++) {
            float v = mx[pg][i];
            v = fmaxf(v, __shfl_xor(v, 1));
            v = fmaxf(v, __shfl_xor(v, 2));
            v = fmaxf(v, __shfl_xor(v, 4));
            v = fmaxf(v, __shfl_xor(v, 8));
            mx[pg][i] = v;
        }
    if (l15 == 0) {
        #pragma unroll
        for (int pg = 0; pg < 4; pg++)
            #pragma unroll
            for (int i = 0; i < 4; i++) {
                int row = rowbase + pg * 16 + lhi * 4 + i;   // [0,4096)
                int n = row >> 10, p = row & 1023;
                sp_part[((size_t)(n * 8 + m) * 8 + qq) * 1024 + p] = mx[pg][i];
            }
    }
}

// --------- Kernel 3: fused fold + scores + bilinear upsample ---------------
// grid (65, 4): bx<64 -> 8-row output band; bx==64 -> scores[n]
__global__ __launch_bounds__(256) void kfinal(const float* __restrict__ sp_part,
                                              const float* __restrict__ mask,
                                              float* __restrict__ out) {
    const int n = blockIdx.y;
    const int bx = blockIdx.x;
    const int t = threadIdx.x;
    float* pix = out + 4;

    if (bx == 64) {  // ---- scores[n] = mean_m max_p dist ----
        __shared__ float smax[4];
        float acc = 0.f;
        for (int m = 0; m < 8; m++) {
            const float* base = sp_part + (size_t)(n * 8 + m) * 8 * 1024;
            float lm = -1e30f;
            #pragma unroll
            for (int i = 0; i < 4; i++) {
                int p = i * 256 + t;
                float dot = -1e30f;
                #pragma unroll
                for (int s = 0; s < 8; s++) dot = fmaxf(dot, base[s * 1024 + p]);
                float d = sqrtf(fmaxf(2.0f - 2.0f * dot, 0.0f)) * 0.5f * mask[n * 1024 + p];
                lm = fmaxf(lm, d);
            }
            #pragma unroll
            for (int d = 32; d; d >>= 1) lm = fmaxf(lm, __shfl_xor(lm, d));
            if ((t & 63) == 0) smax[t >> 6] = lm;
            __syncthreads();
            if (t == 0) acc += fmaxf(fmaxf(smax[0], smax[1]), fmaxf(smax[2], smax[3]));
            __syncthreads();
        }
        if (t == 0) out[n] = acc * 0.125f;
        return;
    }

    // ---- output band: rows [bx*8, bx*8+8); needs 2 consecutive patch rows ----
    __shared__ float sp_row[2][32];
    const int band = bx * 8;
    const int pr_lo = (int)floorf((band + 0.5f) * 0.0625f - 0.5f);
    const int row0 = min(max(pr_lo, 0), 31);
    const int row1 = min(max(pr_lo + 1, 0), 31);
    {
        int v = t >> 2, sub = t & 3;          // 64 values x 4 threads
        int vr = v >> 5, vc = v & 31;
        int p = (vr ? row1 : row0) * 32 + vc;
        float sum = 0.f;
        #pragma unroll
        for (int mi = 0; mi < 2; mi++) {
            int m = sub * 2 + mi;
            const float* base = sp_part + (size_t)(n * 8 + m) * 8 * 1024 + p;
            float dot = -1e30f;
            #pragma unroll
            for (int s = 0; s < 8; s++) dot = fmaxf(dot, base[s * 1024]);
            sum += sqrtf(fmaxf(2.0f - 2.0f * dot, 0.0f)) * 0.5f;
        }
        sum *= mask[n * 1024 + p];
        sum += __shfl_xor(sum, 1);
        sum += __shfl_xor(sum, 2);
        if (sub == 0) sp_row[vr][vc] = sum * 0.125f;
    }
    __syncthreads();
    #pragma unroll
    for (int i = 0; i < 16; i++) {
        int idx = i * 256 + t;
        int yl = idx >> 9, x = idx & 511;
        int y = band + yl;
        float fy = (y + 0.5f) * 0.0625f - 0.5f;
        float ty = fy - (float)pr_lo;          // rows {pr_lo, pr_lo+1}; clamped dup at edges
        float fx = (x + 0.5f) * 0.0625f - 0.5f;
        float xf = floorf(fx);
        float tx = fx - xf;
        int x0 = (int)xf;
        int x0c = min(max(x0, 0), 31), x1c = min(max(x0 + 1, 0), 31);
        float v00 = sp_row[0][x0c], v01 = sp_row[0][x1c];
        float v10 = sp_row[1][x0c], v11 = sp_row[1][x1c];
        float v0 = v00 + tx * (v01 - v00);
        float v1 = v10 + tx * (v11 - v10);
        pix[(size_t)n * 262144 + (size_t)y * 512 + x] = v0 + ty * (v1 - v0);
    }
}

extern "C" void kernel_launch(void* const* d_in, const int* in_sizes, int n_in,
                              void* d_out, int out_size, void* d_ws, size_t ws_size,
                              hipStream_t stream) {
    const float* feats = (const float*)d_in[0];           // [4,1024,128] f32
    const float* nfeats = (const float*)d_in[1];          // [8,1024,128] f32
    const float* mask = (const float*)d_in[2];            // [4,1024] f32
    float* out = (float*)d_out;                           // [4] scores + [4,512,512]

    unsigned short* fb = (unsigned short*)d_ws;                         // 1 MB
    unsigned short* gb = fb + 4096 * 128;                               // 2 MB
    float* sp_part = (float*)((char*)d_ws + 3u * 1024u * 1024u);        // 1 MB

    knorm<<<3072, 256, 0, stream>>>(feats, nfeats, fb, gb);
    kscore<<<dim3(8, 128), 256, 0, stream>>>(fb, gb, sp_part);
    kfinal<<<dim3(65, 4), 256, 0, stream>>>(sp_part, mask, out);
}

// Round 13
// 37.987 us; speedup vs baseline: 3.6502x; 1.0210x over previous
//
#include <hip/hip_runtime.h>

typedef __attribute__((ext_vector_type(8))) short short8;
typedef __attribute__((ext_vector_type(4))) float f32x4;

typedef const __attribute__((address_space(1))) unsigned int glb_u32;
typedef __attribute__((address_space(3))) unsigned int lds_u32;

static __device__ inline unsigned short f2bf(float x) {
    unsigned int u = __float_as_uint(x);
    u = (u + 0x7FFFu + ((u >> 16) & 1u)) >> 16;
    return (unsigned short)u;
}

// ---------------- Kernel 1: L2-normalize rows, cast to bf16 ----------------
__global__ __launch_bounds__(256) void knorm(const float* __restrict__ feats,
                                             const float* __restrict__ nfeats,
                                             unsigned short* __restrict__ fb,
                                             unsigned short* __restrict__ gb) {
    int row = blockIdx.x * 4 + (threadIdx.x >> 6);
    int lane = threadIdx.x & 63;
    const float* src;
    unsigned short* dst;
    if (row < 4096) { src = feats + row * 128;           dst = fb + row * 128; }
    else            { src = nfeats + (row - 4096) * 128; dst = gb + (row - 4096) * 128; }
    float2 v = ((const float2*)src)[lane];
    float ss = v.x * v.x + v.y * v.y;
    #pragma unroll
    for (int d = 32; d; d >>= 1) ss += __shfl_xor(ss, d);
    float inv = 1.0f / sqrtf(ss);
    ushort2 o;
    o.x = f2bf(v.x * inv);
    o.y = f2bf(v.y * inv);
    ((ushort2*)dst)[lane] = o;
}

// ---------------- Kernel 2: partial max_q dot(f[p], g[q]) via MFMA ----------
// 8-phase-template port (m233/m218: 2-phase loops are ~72% structural stall):
// 512 thr = 8 waves (wp=wave>>1 p-subtile, wqt=wave&1 q-half) -> 16 MFMA per
// barrier; TRIPLE-buffered global_load_lds staging, prefetch distance 2,
// counted vmcnt(1) per tile (never 0 mid-loop), setprio around MFMA cluster.
// grid (8 m, 64 = ptile*4+qq) = 512 blocks = 2 independent blocks/CU,
// 16 waves/CU (launch_bounds 512,4 -> VGPR<=128).
__global__ __launch_bounds__(512, 4) void kscore(const unsigned short* __restrict__ fb,
                                                 const unsigned short* __restrict__ gb,
                                                 float* __restrict__ sp_part) {
    __shared__ char gtile[3][8192];          // 3 x 8KB (32 q-rows each)
    const int tid = threadIdx.x;
    const int lane = tid & 63;
    const int wave = tid >> 6;               // 0..7
    const int wp = wave >> 1, wqt = wave & 1;
    const int l15 = lane & 15, lhi = lane >> 4;
    const int m = blockIdx.x;
    const int ptile = blockIdx.y >> 2, qq = blockIdx.y & 3;
    const int rowbase = ptile * 256 + wp * 64;   // global f row in [0,4096)

    const unsigned short* gBase = gb + ((size_t)m * 1024 + qq * 256) * 128;

    // A fragments FIRST (oldest vmem): 4 p-groups x 4 k-groups (64 VGPR)
    short8 a[4][4];
    #pragma unroll
    for (int pg = 0; pg < 4; pg++) {
        const unsigned short* arow = fb + (size_t)(rowbase + pg * 16 + l15) * 128;
        #pragma unroll
        for (int kk = 0; kk < 4; kk++)
            a[pg][kk] = *(const short8*)(arow + kk * 32 + lhi * 8);
    }
    __builtin_amdgcn_sched_barrier(0);

    // async stage 32 q rows (8KB): 1 granule/thread; linear LDS dest, source
    // column pre-permuted so LDS image = (r*256+s*16)^((r&7)<<4) (R2/R5-proven)
    auto stage = [&](int buf, int qb) {
        int r = tid >> 4, s = tid & 15;
        int scol = s ^ (r & 7);
        __builtin_amdgcn_global_load_lds(
            (glb_u32*)(gBase + (size_t)(qb + r) * 128 + scol * 8),
            (lds_u32*)(gtile[buf] + tid * 16), 16, 0, 0);
    };

    stage(0, 0);
    stage(1, 32);

    f32x4 mx[4];
    #pragma unroll
    for (int pg = 0; pg < 4; pg++)
        #pragma unroll
        for (int i = 0; i < 4; i++) mx[pg][i] = -1e30f;

    // prologue: A-loads + stage0 done, stage1 left in flight
    asm volatile("s_waitcnt vmcnt(1)" ::: "memory");
    __builtin_amdgcn_s_barrier();

    #pragma unroll
    for (int t = 0; t < 8; t++) {
        // entry invariant: tile t landed (vmcnt counted + barrier), t+1 flying
        if (t + 2 < 8) stage((t + 2) % 3, (t + 2) * 32);
        __builtin_amdgcn_sched_barrier(0);
        // ds-read this wave's 16-row q-subtile (4 x b128)
        const char* tp = gtile[t % 3];
        const int r = wqt * 16 + l15;
        const int rowoff = r * 256;
        const int swz = (r & 7) << 4;
        short8 b0 = *(const short8*)(tp + ((rowoff +   0 + lhi * 16) ^ swz));
        short8 b1 = *(const short8*)(tp + ((rowoff +  64 + lhi * 16) ^ swz));
        short8 b2 = *(const short8*)(tp + ((rowoff + 128 + lhi * 16) ^ swz));
        short8 b3 = *(const short8*)(tp + ((rowoff + 192 + lhi * 16) ^ swz));
        asm volatile("s_waitcnt lgkmcnt(0)" ::: "memory");
        __builtin_amdgcn_sched_barrier(0);
        __builtin_amdgcn_s_setprio(1);
        f32x4 acc[4];
        #pragma unroll
        for (int pg = 0; pg < 4; pg++) {
            #pragma unroll
            for (int i = 0; i < 4; i++) acc[pg][i] = 0.f;
            acc[pg] = __builtin_amdgcn_mfma_f32_16x16x32_bf16(a[pg][0], b0, acc[pg], 0, 0, 0);
            acc[pg] = __builtin_amdgcn_mfma_f32_16x16x32_bf16(a[pg][1], b1, acc[pg], 0, 0, 0);
            acc[pg] = __builtin_amdgcn_mfma_f32_16x16x32_bf16(a[pg][2], b2, acc[pg], 0, 0, 0);
            acc[pg] = __builtin_amdgcn_mfma_f32_16x16x32_bf16(a[pg][3], b3, acc[pg], 0, 0, 0);
        }
        __builtin_amdgcn_s_setprio(0);
        #pragma unroll
        for (int pg = 0; pg < 4; pg++)
            #pragma unroll
            for (int i = 0; i < 4; i++) mx[pg][i] = fmaxf(mx[pg][i], acc[pg][i]);
        // ensure tile t+1 landed before next phase reads; keep t+2 in flight
        if (t < 6)      asm volatile("s_waitcnt vmcnt(1)" ::: "memory");
        else if (t == 6) asm volatile("s_waitcnt vmcnt(0)" ::: "memory");
        if (t < 7) __builtin_amdgcn_s_barrier();
    }

    // reduce max over the 16 q-columns (C/D col = lane&15)
    #pragma unroll
    for (int pg = 0; pg < 4; pg++)
        #pragma unroll
        for (int i = 0; i < 4; i++) {
            float v = mx[pg][i];
            v = fmaxf(v, __shfl_xor(v, 1));
            v = fmaxf(v, __shfl_xor(v, 2));
            v = fmaxf(v, __shfl_xor(v, 4));
            v = fmaxf(v, __shfl_xor(v, 8));
            mx[pg][i] = v;
        }
    if (l15 == 0) {
        // waves sharing wp cover DISJOINT q halves -> slot = qq (wqt folded via
        // separate writes? NO: wqt0/wqt1 are different q halves of the SAME qq
        // tile-set... each wave covered rows wqt*16+ of every 32-row tile ->
        // partials differ per wqt -> slot = qq*2+wqt (8 slots, kfinal folds 8)
        const int slot = qq * 2 + wqt;
        #pragma unroll
        for (int pg = 0; pg < 4; pg++)
            #pragma unroll
            for (int i = 0; i < 4; i++) {
                int row = rowbase + pg * 16 + lhi * 4 + i;   // [0,4096)
                int n = row >> 10, p = row & 1023;
                sp_part[((size_t)(n * 8 + m) * 8 + slot) * 1024 + p] = mx[pg][i];
            }
    }
}

// --------- Kernel 3: fused fold(8 slots) + scores + bilinear upsample ------
// grid (65, 4): bx<64 -> 8-row output band; bx==64 -> scores[n]
__global__ __launch_bounds__(256) void kfinal(const float* __restrict__ sp_part,
                                              const float* __restrict__ mask,
                                              float* __restrict__ out) {
    const int n = blockIdx.y;
    const int bx = blockIdx.x;
    const int t = threadIdx.x;
    float* pix = out + 4;

    if (bx == 64) {  // ---- scores[n] = mean_m max_p dist ----
        __shared__ float smax[4];
        float acc = 0.f;
        for (int m = 0; m < 8; m++) {
            const float* base = sp_part + (size_t)(n * 8 + m) * 8 * 1024;
            float lm = -1e30f;
            #pragma unroll
            for (int i = 0; i < 4; i++) {
                int p = i * 256 + t;
                float dot = -1e30f;
                #pragma unroll
                for (int s = 0; s < 8; s++) dot = fmaxf(dot, base[s * 1024 + p]);
                float d = sqrtf(fmaxf(2.0f - 2.0f * dot, 0.0f)) * 0.5f * mask[n * 1024 + p];
                lm = fmaxf(lm, d);
            }
            #pragma unroll
            for (int d = 32; d; d >>= 1) lm = fmaxf(lm, __shfl_xor(lm, d));
            if ((t & 63) == 0) smax[t >> 6] = lm;
            __syncthreads();
            if (t == 0) acc += fmaxf(fmaxf(smax[0], smax[1]), fmaxf(smax[2], smax[3]));
            __syncthreads();
        }
        if (t == 0) out[n] = acc * 0.125f;
        return;
    }

    // ---- output band: rows [bx*8, bx*8+8); needs 2 consecutive patch rows ----
    __shared__ float sp_row[2][32];
    const int band = bx * 8;
    const int pr_lo = (int)floorf((band + 0.5f) * 0.0625f - 0.5f);
    const int row0 = min(max(pr_lo, 0), 31);
    const int row1 = min(max(pr_lo + 1, 0), 31);
    {
        int v = t >> 2, sub = t & 3;          // 64 values x 4 threads
        int vr = v >> 5, vc = v & 31;
        int p = (vr ? row1 : row0) * 32 + vc;
        float sum = 0.f;
        #pragma unroll
        for (int mi = 0; mi < 2; mi++) {
            int m = sub * 2 + mi;
            const float* base = sp_part + (size_t)(n * 8 + m) * 8 * 1024 + p;
            float dot = -1e30f;
            #pragma unroll
            for (int s = 0; s < 8; s++) dot = fmaxf(dot, base[s * 1024]);
            sum += sqrtf(fmaxf(2.0f - 2.0f * dot, 0.0f)) * 0.5f;
        }
        sum *= mask[n * 1024 + p];
        sum += __shfl_xor(sum, 1);
        sum += __shfl_xor(sum, 2);
        if (sub == 0) sp_row[vr][vc] = sum * 0.125f;
    }
    __syncthreads();
    #pragma unroll
    for (int i = 0; i < 16; i++) {
        int idx = i * 256 + t;
        int yl = idx >> 9, x = idx & 511;
        int y = band + yl;
        float fy = (y + 0.5f) * 0.0625f - 0.5f;
        float ty = fy - (float)pr_lo;          // rows {pr_lo, pr_lo+1}; clamped dup at edges
        float fx = (x + 0.5f) * 0.0625f - 0.5f;
        float xf = floorf(fx);
        float tx = fx - xf;
        int x0 = (int)xf;
        int x0c = min(max(x0, 0), 31), x1c = min(max(x0 + 1, 0), 31);
        float v00 = sp_row[0][x0c], v01 = sp_row[0][x1c];
        float v10 = sp_row[1][x0c], v11 = sp_row[1][x1c];
        float v0 = v00 + tx * (v01 - v00);
        float v1 = v10 + tx * (v11 - v10);
        pix[(size_t)n * 262144 + (size_t)y * 512 + x] = v0 + ty * (v1 - v0);
    }
}

extern "C" void kernel_launch(void* const* d_in, const int* in_sizes, int n_in,
                              void* d_out, int out_size, void* d_ws, size_t ws_size,
                              hipStream_t stream) {
    const float* feats = (const float*)d_in[0];           // [4,1024,128] f32
    const float* nfeats = (const float*)d_in[1];          // [8,1024,128] f32
    const float* mask = (const float*)d_in[2];            // [4,1024] f32
    float* out = (float*)d_out;                           // [4] scores + [4,512,512]

    unsigned short* fb = (unsigned short*)d_ws;                         // 1 MB
    unsigned short* gb = fb + 4096 * 128;                               // 2 MB
    float* sp_part = (float*)((char*)d_ws + 3u * 1024u * 1024u);        // 1 MB

    knorm<<<3072, 256, 0, stream>>>(feats, nfeats, fb, gb);
    kscore<<<dim3(8, 64), 512, 0, stream>>>(fb, gb, sp_part);
    kfinal<<<dim3(65, 4), 256, 0, stream>>>(sp_part, mask, out);
}

// Round 14
// 33.911 us; speedup vs baseline: 4.0890x; 1.1202x over previous
//
#include <hip/hip_runtime.h>

typedef __attribute__((ext_vector_type(8))) short short8;
typedef __attribute__((ext_vector_type(4))) float f32x4;
typedef __attribute__((ext_vector_type(4))) unsigned int u32x4;

static __device__ inline unsigned short f2bf(float x) {
    unsigned int u = __float_as_uint(x);
    u = (u + 0x7FFFu + ((u >> 16) & 1u)) >> 16;
    return (unsigned short)u;
}

static __device__ inline unsigned int pk(float a, float b, float inv) {
    return (unsigned int)f2bf(a * inv) | ((unsigned int)f2bf(b * inv) << 16);
}

// ------------- Kernel 1: fused normalize + partial max_q dot via MFMA -------
// Reads feats/nfeats (d_in) DIRECTLY as f32, normalizes in-kernel, packs bf16
// into the proven XOR-swizzled LDS image.  d_ws traffic (uncached-behaving,
// ~3.7 TB/s ceiling measured R3/R7/R11) reduced to sp_part (512 KB) only.
// Geometry = R9 (best): grid (8 m, 64 = ptile*4+qq), 256 thr = 4 waves,
// block = 256p x 256q, 8 phases x 32 q-rows, depth-2 reg-staged pipeline,
// 32 MFMA per barrier per wave.
__global__ __launch_bounds__(256, 2) void kscore(const float* __restrict__ feats,
                                                 const float* __restrict__ nfeats,
                                                 float* __restrict__ sp_part) {
    __shared__ char gtile[2][8192];          // 2 x 8KB bf16, swizzled image
    const int tid = threadIdx.x;
    const int lane = tid & 63;
    const int wave = tid >> 6;               // 0..3 = p-subtile
    const int l15 = lane & 15, lhi = lane >> 4;
    const int m = blockIdx.x;                // XCD-pinned gb slice
    const int ptile = blockIdx.y >> 2, qq = blockIdx.y & 3;
    const int rowbase = ptile * 256 + wave * 64;   // flattened f row [0,4096)

    const float* gBase = nfeats + ((size_t)m * 1024 + qq * 256) * 128;

    // B staging: 2 rows/thread (r0, r0+16), 8 f32 each at col s0*8; row's 16
    // threads are 16 consecutive lanes -> sumsq butterfly shfl_xor 1,2,4,8.
    const int r0 = tid >> 4, s0 = tid & 15;
    const int r1 = r0 + 16;
    const float* gsrc0 = gBase + (size_t)r0 * 128 + s0 * 8;
    const float* gsrc1 = gBase + (size_t)r1 * 128 + s0 * 8;
    const int wofs0 = (r0 * 256 + s0 * 16) ^ ((r0 & 7) << 4);
    const int wofs1 = (r1 * 256 + s0 * 16) ^ ((r1 & 7) << 4);

    // load 8 f32 of one staged row -> normalize -> packed bf16 16B
    auto ldrow = [](const float* p, f32x4& x, f32x4& y) {
        x = *(const f32x4*)(p);
        y = *(const f32x4*)(p + 4);
    };
    auto rownorm = [&](const f32x4& x, const f32x4& y) {
        float ss = x[0]*x[0] + x[1]*x[1] + x[2]*x[2] + x[3]*x[3]
                 + y[0]*y[0] + y[1]*y[1] + y[2]*y[2] + y[3]*y[3];
        ss += __shfl_xor(ss, 1);
        ss += __shfl_xor(ss, 2);
        ss += __shfl_xor(ss, 4);
        ss += __shfl_xor(ss, 8);
        return 1.0f / sqrtf(ss);
    };
    auto packrow = [&](const f32x4& x, const f32x4& y, float inv) {
        u32x4 o;
        o.x = pk(x[0], x[1], inv);
        o.y = pk(x[2], x[3], inv);
        o.z = pk(y[0], y[1], inv);
        o.w = pk(y[2], y[3], inv);
        return o;
    };

    // ---- prologue: issue B tile0+tile1 loads, then A load+normalize ----
    f32x4 t0xa, t0ya, t0xb, t0yb, t1xa, t1ya, t1xb, t1yb;
    ldrow(gsrc0, t0xa, t0ya); ldrow(gsrc1, t0xb, t0yb);
    ldrow(gsrc0 + 32 * 128, t1xa, t1ya); ldrow(gsrc1 + 32 * 128, t1xb, t1yb);

    // A fragments: 4 p-groups; lane holds 32 f32 of row (pg,l15); norm across
    // the 4 lanes sharing l15 (shfl_xor 16,32); pack to 4x short8.
    short8 a[4][4];
    #pragma unroll
    for (int pg = 0; pg < 4; pg++) {
        const float* arow = feats + (size_t)(rowbase + pg * 16 + l15) * 128 + lhi * 8;
        f32x4 vx[4], vy[4];
        float ss = 0.f;
        #pragma unroll
        for (int kk = 0; kk < 4; kk++) {
            vx[kk] = *(const f32x4*)(arow + kk * 32);
            vy[kk] = *(const f32x4*)(arow + kk * 32 + 4);
            #pragma unroll
            for (int j = 0; j < 4; j++) ss += vx[kk][j]*vx[kk][j] + vy[kk][j]*vy[kk][j];
        }
        ss += __shfl_xor(ss, 16);
        ss += __shfl_xor(ss, 32);
        float inv = 1.0f / sqrtf(ss);
        #pragma unroll
        for (int kk = 0; kk < 4; kk++) {
            u32x4 o = packrow(vx[kk], vy[kk], inv);
            a[pg][kk] = *(short8*)&o;
        }
    }

    // normalize+write tile0 (loads already landed under the A work)
    {
        float i0 = rownorm(t0xa, t0ya);
        *(u32x4*)(gtile[0] + wofs0) = packrow(t0xa, t0ya, i0);
        float i1 = rownorm(t0xb, t0yb);
        *(u32x4*)(gtile[0] + wofs1) = packrow(t0xb, t0yb, i1);
    }

    f32x4 mx[4];
    #pragma unroll
    for (int pg = 0; pg < 4; pg++)
        #pragma unroll
        for (int i = 0; i < 4; i++) mx[pg][i] = -1e30f;

    asm volatile("s_waitcnt lgkmcnt(0)" ::: "memory");
    __builtin_amdgcn_s_barrier();

    #pragma unroll
    for (int t = 0; t < 8; t++) {
        __builtin_amdgcn_sched_barrier(0);
        // issue tile t+2 loads (stay in flight across this phase)
        f32x4 n2xa, n2ya, n2xb, n2yb;
        if (t < 6) {
            ldrow(gsrc0 + (size_t)(t + 2) * 32 * 128, n2xa, n2ya);
            ldrow(gsrc1 + (size_t)(t + 2) * 32 * 128, n2xb, n2yb);
        }
        // normalize + write tile t+1 into the buffer consumed last phase
        if (t < 7) {
            float i0 = rownorm(t1xa, t1ya);
            *(u32x4*)(gtile[(t + 1) & 1] + wofs0) = packrow(t1xa, t1ya, i0);
            float i1 = rownorm(t1xb, t1yb);
            *(u32x4*)(gtile[(t + 1) & 1] + wofs1) = packrow(t1xb, t1yb, i1);
        }
        // compute tile t: 2 q-subtiles x 4 kk x 4 pg = 32 MFMA
        const char* tp = gtile[t & 1];
        #pragma unroll
        for (int qt = 0; qt < 2; qt++) {
            const int r = qt * 16 + l15;
            const int rowoff = r * 256;
            const int swz = (r & 7) << 4;
            f32x4 acc[4];
            #pragma unroll
            for (int pg = 0; pg < 4; pg++)
                #pragma unroll
                for (int i = 0; i < 4; i++) acc[pg][i] = 0.f;
            #pragma unroll
            for (int kk = 0; kk < 4; kk++) {
                short8 b = *(const short8*)(tp + ((rowoff + kk * 64 + lhi * 16) ^ swz));
                #pragma unroll
                for (int pg = 0; pg < 4; pg++)
                    acc[pg] = __builtin_amdgcn_mfma_f32_16x16x32_bf16(a[pg][kk], b, acc[pg], 0, 0, 0);
            }
            #pragma unroll
            for (int pg = 0; pg < 4; pg++)
                #pragma unroll
                for (int i = 0; i < 4; i++) mx[pg][i] = fmaxf(mx[pg][i], acc[pg][i]);
        }
        if (t < 6) { t1xa = n2xa; t1ya = n2ya; t1xb = n2xb; t1yb = n2yb; }
        asm volatile("s_waitcnt lgkmcnt(0)" ::: "memory");
        __builtin_amdgcn_s_barrier();
    }

    // reduce max over the 16 q-columns (C/D col = lane&15)
    #pragma unroll
    for (int pg = 0; pg < 4; pg++)
        #pragma unroll
        for (int i = 0; i < 4; i++) {
            float v = mx[pg][i];
            v = fmaxf(v, __shfl_xor(v, 1));
            v = fmaxf(v, __shfl_xor(v, 2));
            v = fmaxf(v, __shfl_xor(v, 4));
            v = fmaxf(v, __shfl_xor(v, 8));
            mx[pg][i] = v;
        }
    if (l15 == 0) {
        #pragma unroll
        for (int pg = 0; pg < 4; pg++)
            #pragma unroll
            for (int i = 0; i < 4; i++) {
                int row = rowbase + pg * 16 + lhi * 4 + i;   // [0,4096)
                int n = row >> 10, p = row & 1023;
                sp_part[((size_t)(n * 8 + m) * 4 + qq) * 1024 + p] = mx[pg][i];
            }
    }
}

// --------- Kernel 2: fused fold + scores + bilinear upsample ---------------
// grid (65, 4): bx<64 -> 8-row output band; bx==64 -> scores[n]
__global__ __launch_bounds__(256) void kfinal(const float* __restrict__ sp_part,
                                              const float* __restrict__ mask,
                                              float* __restrict__ out) {
    const int n = blockIdx.y;
    const int bx = blockIdx.x;
    const int t = threadIdx.x;
    float* pix = out + 4;

    if (bx == 64) {  // ---- scores[n] = mean_m max_p dist ----
        __shared__ float smax[4];
        float acc = 0.f;
        for (int m = 0; m < 8; m++) {
            const float* base = sp_part + (size_t)(n * 8 + m) * 4 * 1024;
            float lm = -1e30f;
            #pragma unroll
            for (int i = 0; i < 4; i++) {
                int p = i * 256 + t;
                float dot = fmaxf(fmaxf(base[p], base[1024 + p]),
                                  fmaxf(base[2048 + p], base[3072 + p]));
                float d = sqrtf(fmaxf(2.0f - 2.0f * dot, 0.0f)) * 0.5f * mask[n * 1024 + p];
                lm = fmaxf(lm, d);
            }
            #pragma unroll
            for (int d = 32; d; d >>= 1) lm = fmaxf(lm, __shfl_xor(lm, d));
            if ((t & 63) == 0) smax[t >> 6] = lm;
            __syncthreads();
            if (t == 0) acc += fmaxf(fmaxf(smax[0], smax[1]), fmaxf(smax[2], smax[3]));
            __syncthreads();
        }
        if (t == 0) out[n] = acc * 0.125f;
        return;
    }

    // ---- output band: rows [bx*8, bx*8+8); needs 2 consecutive patch rows ----
    __shared__ float sp_row[2][32];
    const int band = bx * 8;
    const int pr_lo = (int)floorf((band + 0.5f) * 0.0625f - 0.5f);
    const int row0 = min(max(pr_lo, 0), 31);
    const int row1 = min(max(pr_lo + 1, 0), 31);
    {
        int v = t >> 2, sub = t & 3;          // 64 values x 4 threads
        int vr = v >> 5, vc = v & 31;
        int p = (vr ? row1 : row0) * 32 + vc;
        float sum = 0.f;
        #pragma unroll
        for (int mi = 0; mi < 2; mi++) {
            int m = sub * 2 + mi;
            const float* base = sp_part + (size_t)(n * 8 + m) * 4 * 1024 + p;
            float dot = fmaxf(fmaxf(base[0], base[1024]),
                              fmaxf(base[2048], base[3072]));
            sum += sqrtf(fmaxf(2.0f - 2.0f * dot, 0.0f)) * 0.5f;
        }
        sum *= mask[n * 1024 + p];
        sum += __shfl_xor(sum, 1);
        sum += __shfl_xor(sum, 2);
        if (sub == 0) sp_row[vr][vc] = sum * 0.125f;
    }
    __syncthreads();
    #pragma unroll
    for (int i = 0; i < 16; i++) {
        int idx = i * 256 + t;
        int yl = idx >> 9, x = idx & 511;
        int y = band + yl;
        float fy = (y + 0.5f) * 0.0625f - 0.5f;
        float ty = fy - (float)pr_lo;          // rows {pr_lo, pr_lo+1}; clamped dup at edges
        float fx = (x + 0.5f) * 0.0625f - 0.5f;
        float xf = floorf(fx);
        float tx = fx - xf;
        int x0 = (int)xf;
        int x0c = min(max(x0, 0), 31), x1c = min(max(x0 + 1, 0), 31);
        float v00 = sp_row[0][x0c], v01 = sp_row[0][x1c];
        float v10 = sp_row[1][x0c], v11 = sp_row[1][x1c];
        float v0 = v00 + tx * (v01 - v00);
        float v1 = v10 + tx * (v11 - v10);
        pix[(size_t)n * 262144 + (size_t)y * 512 + x] = v0 + ty * (v1 - v0);
    }
}

extern "C" void kernel_launch(void* const* d_in, const int* in_sizes, int n_in,
                              void* d_out, int out_size, void* d_ws, size_t ws_size,
                              hipStream_t stream) {
    const float* feats = (const float*)d_in[0];           // [4,1024,128] f32
    const float* nfeats = (const float*)d_in[1];          // [8,1024,128] f32
    const float* mask = (const float*)d_in[2];            // [4,1024] f32
    float* out = (float*)d_out;                           // [4] scores + [4,512,512]

    float* sp_part = (float*)d_ws;                        // 512 KB only

    kscore<<<dim3(8, 64), 256, 0, stream>>>(feats, nfeats, sp_part);
    kfinal<<<dim3(65, 4), 256, 0, stream>>>(sp_part, mask, out);
}